// Round 2
// baseline (2334.478 us; speedup 1.0000x reference)
//
#include <hip/hip_runtime.h>
#include <stdint.h>

// Problem constants (fixed by the reference).
static constexpr int kN   = 50000;   // nodes
static constexpr int kFin = 128;
static constexpr int kHid = 128;
static constexpr int kOut = 64;

// ---------------- threefry2x32-20 (verified vs Random123 KAT) ----------------
__device__ __forceinline__ uint32_t rotl32(uint32_t v, uint32_t r) {
  return (v << r) | (v >> (32u - r));
}

__device__ __forceinline__ uint2 threefry2x32(uint32_t k0, uint32_t k1,
                                              uint32_t x0, uint32_t x1) {
  const uint32_t k2 = k0 ^ k1 ^ 0x1BD11BDAu;
  x0 += k0; x1 += k1;
#define TFR(r) { x0 += x1; x1 = rotl32(x1, r); x1 ^= x0; }
  TFR(13u) TFR(15u) TFR(26u) TFR(6u)
  x0 += k1; x1 += k2 + 1u;
  TFR(17u) TFR(29u) TFR(16u) TFR(24u)
  x0 += k2; x1 += k0 + 2u;
  TFR(13u) TFR(15u) TFR(26u) TFR(6u)
  x0 += k0; x1 += k1 + 3u;
  TFR(17u) TFR(29u) TFR(16u) TFR(24u)
  x0 += k1; x1 += k2 + 4u;
  TFR(13u) TFR(15u) TFR(26u) TFR(6u)
  x0 += k2; x1 += k0 + 5u;
#undef TFR
  return make_uint2(x0, x1);
}

// ---------------- scatter-add: agg[dst[e]] += rows[src[e]] ----------------
// 32 threads per edge; each thread handles 4 consecutive features (float4).
__global__ __launch_bounds__(256) void scatter_add_rows(
    const float* __restrict__ rows, const int* __restrict__ src,
    const int* __restrict__ dst, float* __restrict__ agg, int E) {
  int idx = blockIdx.x * 256 + threadIdx.x;
  int e = idx >> 5;
  if (e >= E) return;
  int f = (idx & 31) << 2;
  int s = src[e];
  int d = dst[e];
  const float4 v = *reinterpret_cast<const float4*>(rows + (size_t)s * 128 + f);
  float* p = agg + (size_t)d * 128 + f;
  atomicAdd(p + 0, v.x);
  atomicAdd(p + 1, v.y);
  atomicAdd(p + 2, v.z);
  atomicAdd(p + 3, v.w);
}

// ---------------- layer 1: h = dropout(relu((x+agg) @ W1 + b1)) ----------------
// Block = 256 threads = 4 waves; 2 nodes per iteration (2 waves per node).
// W1 (128x128 f32 = 64 KB) staged in LDS; input row held 2 floats/lane,
// broadcast via __shfl.
__global__ __launch_bounds__(256) void gin_layer1(
    const float* __restrict__ x, const float* __restrict__ agg,
    const float* __restrict__ W1, const float* __restrict__ b1,
    float* __restrict__ h) {
  __shared__ float Wl[128 * 128];  // 64 KB
  for (int i = threadIdx.x; i < 128 * 128 / 4; i += 256)
    reinterpret_cast<float4*>(Wl)[i] = reinterpret_cast<const float4*>(W1)[i];
  __syncthreads();

  const int o    = threadIdx.x & 127;  // output feature
  const int lane = threadIdx.x & 63;
  const int nl   = threadIdx.x >> 7;   // 0..1: which node of the pair
  const float bias = b1[o];

  for (int n0 = blockIdx.x * 2; n0 < kN; n0 += gridDim.x * 2) {
    const int n = n0 + nl;
    const size_t rb = (size_t)n * 128;
    // (1+1e-9) rounds to 1.0f in fp32, so the GIN self-term is just x.
    const float r0 = x[rb + lane]      + agg[rb + lane];
    const float r1 = x[rb + 64 + lane] + agg[rb + 64 + lane];

    float acc = bias;
#pragma unroll
    for (int k = 0; k < 64; ++k)
      acc = fmaf(__shfl(r0, k, 64), Wl[k * 128 + o], acc);
#pragma unroll
    for (int k = 0; k < 64; ++k)
      acc = fmaf(__shfl(r1, k, 64), Wl[(k + 64) * 128 + o], acc);

    acc = fmaxf(acc, 0.0f);

    // JAX dropout mask, jax_threefry_partitionable=True (default since 0.5.0):
    // bits[j] = out0 ^ out1 of threefry2x32(key=(0,42), ctr=(hi32(j), lo32(j))).
    // j < 2^32 here so ctr = (0, j). keep iff uniform < 0.5 iff MSB(bits)==0;
    // kept values scaled by 1/(1-p) = 2.
    const uint32_t j = (uint32_t)n * 128u + (uint32_t)o;
    const uint2 r = threefry2x32(0u, 42u, 0u, j);
    const uint32_t bits = r.x ^ r.y;
    h[rb + o] = (bits >> 31) ? 0.0f : (acc * 2.0f);
  }
}

// ---------------- layer 2: out = (h+agg) @ W2 + b2 ----------------
// Block = 256 threads = 4 waves; 4 nodes per iteration (1 wave per node).
__global__ __launch_bounds__(256) void gin_layer2(
    const float* __restrict__ h, const float* __restrict__ agg,
    const float* __restrict__ W2, const float* __restrict__ b2,
    float* __restrict__ out) {
  __shared__ float Wl[128 * 64];  // 32 KB
  for (int i = threadIdx.x; i < 128 * 64 / 4; i += 256)
    reinterpret_cast<float4*>(Wl)[i] = reinterpret_cast<const float4*>(W2)[i];
  __syncthreads();

  const int o  = threadIdx.x & 63;  // output feature == lane
  const int nl = threadIdx.x >> 6;  // 0..3: which node of the quad
  const float bias = b2[o];

  for (int n0 = blockIdx.x * 4; n0 < kN; n0 += gridDim.x * 4) {
    const int n = n0 + nl;
    const size_t rb = (size_t)n * 128;
    const float r0 = h[rb + o]      + agg[rb + o];
    const float r1 = h[rb + 64 + o] + agg[rb + 64 + o];

    float acc = bias;
#pragma unroll
    for (int k = 0; k < 64; ++k)
      acc = fmaf(__shfl(r0, k, 64), Wl[k * 64 + o], acc);
#pragma unroll
    for (int k = 0; k < 64; ++k)
      acc = fmaf(__shfl(r1, k, 64), Wl[(k + 64) * 64 + o], acc);

    out[(size_t)n * 64 + o] = acc;
  }
}

// ---------------- launch ----------------
extern "C" void kernel_launch(void* const* d_in, const int* in_sizes, int n_in,
                              void* d_out, int out_size, void* d_ws, size_t ws_size,
                              hipStream_t stream) {
  const float* x  = (const float*)d_in[0];
  const int*   ei = (const int*)d_in[1];
  const float* W1 = (const float*)d_in[2];
  const float* b1 = (const float*)d_in[3];
  const float* W2 = (const float*)d_in[4];
  const float* b2 = (const float*)d_in[5];
  float* out = (float*)d_out;

  const int E = in_sizes[1] / 2;      // edge_index is (2, E)
  const int* src = ei;
  const int* dst = ei + E;

  float* agg = (float*)d_ws;                       // N*128 f32 = 25.6 MB
  float* h   = agg + (size_t)kN * kHid;            // N*128 f32 = 25.6 MB
  const size_t aggBytes = (size_t)kN * kHid * sizeof(float);

  const int sblocks = (E * 32 + 255) / 256;

  hipMemsetAsync(agg, 0, aggBytes, stream);
  scatter_add_rows<<<sblocks, 256, 0, stream>>>(x, src, dst, agg, E);
  gin_layer1<<<512, 256, 0, stream>>>(x, agg, W1, b1, h);
  hipMemsetAsync(agg, 0, aggBytes, stream);
  scatter_add_rows<<<sblocks, 256, 0, stream>>>(h, src, dst, agg, E);
  gin_layer2<<<512, 256, 0, stream>>>(h, agg, W2, b2, out);
}

// Round 3
// 974.052 us; speedup vs baseline: 2.3967x; 2.3967x over previous
//
#include <hip/hip_runtime.h>
#include <stdint.h>

static constexpr int kN   = 50000;   // nodes
static constexpr int kCap = 64;      // adjacency capacity per node (Poisson(12) tail @64 ~ 1e-25)

// ---------------- threefry2x32-20 (verified vs Random123 KAT) ----------------
__device__ __forceinline__ uint32_t rotl32(uint32_t v, uint32_t r) {
  return (v << r) | (v >> (32u - r));
}

__device__ __forceinline__ uint2 threefry2x32(uint32_t k0, uint32_t k1,
                                              uint32_t x0, uint32_t x1) {
  const uint32_t k2 = k0 ^ k1 ^ 0x1BD11BDAu;
  x0 += k0; x1 += k1;
#define TFR(r) { x0 += x1; x1 = rotl32(x1, r); x1 ^= x0; }
  TFR(13u) TFR(15u) TFR(26u) TFR(6u)
  x0 += k1; x1 += k2 + 1u;
  TFR(17u) TFR(29u) TFR(16u) TFR(24u)
  x0 += k2; x1 += k0 + 2u;
  TFR(13u) TFR(15u) TFR(26u) TFR(6u)
  x0 += k0; x1 += k1 + 3u;
  TFR(17u) TFR(29u) TFR(16u) TFR(24u)
  x0 += k1; x1 += k2 + 4u;
  TFR(13u) TFR(15u) TFR(26u) TFR(6u)
  x0 += k2; x1 += k0 + 5u;
#undef TFR
  return make_uint2(x0, x1);
}

// JAX dropout bit (jax_threefry_partitionable default): keep iff MSB==0 of
// out0^out1 of threefry((0,42), (0, j)).
__device__ __forceinline__ bool drop_elem(uint32_t j) {
  const uint2 r = threefry2x32(0u, 42u, 0u, j);
  return ((r.x ^ r.y) >> 31) != 0u;
}

// ---------------- adjacency build: adj[d*64 + slot] = src ----------------
__global__ __launch_bounds__(256) void build_adj(
    const int* __restrict__ src, const int* __restrict__ dst,
    int* __restrict__ cnt, int* __restrict__ adj, int E) {
  int e = blockIdx.x * 256 + threadIdx.x;
  if (e >= E) return;
  int d = dst[e];
  int slot = atomicAdd(&cnt[d], 1);
  if (slot < kCap) adj[d * kCap + slot] = src[e];
}

// ---------------- fused layer 1 ----------------
// h[n] = dropout(relu((x[n] + sum_{s in adj[n]} x[s]) @ W1 + b1))
// Block = 512 (8 waves); each wave processes 2 nodes per iteration.
// Lane holds features {lane, lane+64}; W1 in LDS (64 KB).
__global__ __launch_bounds__(512) void gin_fused1(
    const float* __restrict__ x, const int* __restrict__ adj,
    const int* __restrict__ cnt, const float* __restrict__ W1,
    const float* __restrict__ b1, float* __restrict__ h) {
  __shared__ float Wl[128 * 128];  // 64 KB
  for (int i = threadIdx.x; i < 128 * 128 / 4; i += 512)
    reinterpret_cast<float4*>(Wl)[i] = reinterpret_cast<const float4*>(W1)[i];
  __syncthreads();

  const int lane = threadIdx.x & 63;
  const int wid  = threadIdx.x >> 6;  // 0..7
  const float bias0 = b1[lane];
  const float bias1 = b1[64 + lane];

  for (int p = blockIdx.x * 8 + wid; p < kN / 2; p += gridDim.x * 8) {
    const int nA = p * 2, nB = p * 2 + 1;
    const size_t rbA = (size_t)nA * 128, rbB = (size_t)nB * 128;

    // self term ((1+1e-9) rounds to 1.0f) + gather
    float rA0 = x[rbA + lane], rA1 = x[rbA + 64 + lane];
    float rB0 = x[rbB + lane], rB1 = x[rbB + 64 + lane];
    const int dA = __builtin_amdgcn_readfirstlane(cnt[nA]);
    const int dB = __builtin_amdgcn_readfirstlane(cnt[nB]);
    const int* alA = adj + nA * kCap;
    const int* alB = adj + nB * kCap;
    int e = 0;
    for (; e + 2 <= dA; e += 2) {
      const int s0 = __builtin_amdgcn_readfirstlane(alA[e]);
      const int s1 = __builtin_amdgcn_readfirstlane(alA[e + 1]);
      rA0 += x[(size_t)s0 * 128 + lane] + x[(size_t)s1 * 128 + lane];
      rA1 += x[(size_t)s0 * 128 + 64 + lane] + x[(size_t)s1 * 128 + 64 + lane];
    }
    if (e < dA) {
      const int s = __builtin_amdgcn_readfirstlane(alA[e]);
      rA0 += x[(size_t)s * 128 + lane];
      rA1 += x[(size_t)s * 128 + 64 + lane];
    }
    e = 0;
    for (; e + 2 <= dB; e += 2) {
      const int s0 = __builtin_amdgcn_readfirstlane(alB[e]);
      const int s1 = __builtin_amdgcn_readfirstlane(alB[e + 1]);
      rB0 += x[(size_t)s0 * 128 + lane] + x[(size_t)s1 * 128 + lane];
      rB1 += x[(size_t)s0 * 128 + 64 + lane] + x[(size_t)s1 * 128 + 64 + lane];
    }
    if (e < dB) {
      const int s = __builtin_amdgcn_readfirstlane(alB[e]);
      rB0 += x[(size_t)s * 128 + lane];
      rB1 += x[(size_t)s * 128 + 64 + lane];
    }

    // GEMM: outputs {lane, lane+64} for both nodes; W read once per k.
    float aA0 = bias0, aA1 = bias1, aB0 = bias0, aB1 = bias1;
#pragma unroll
    for (int k = 0; k < 64; ++k) {
      const float w0 = Wl[k * 128 + lane];
      const float w1 = Wl[k * 128 + 64 + lane];
      const float vA = __shfl(rA0, k, 64);
      const float vB = __shfl(rB0, k, 64);
      aA0 = fmaf(vA, w0, aA0); aA1 = fmaf(vA, w1, aA1);
      aB0 = fmaf(vB, w0, aB0); aB1 = fmaf(vB, w1, aB1);
    }
#pragma unroll
    for (int k = 0; k < 64; ++k) {
      const float w0 = Wl[(64 + k) * 128 + lane];
      const float w1 = Wl[(64 + k) * 128 + 64 + lane];
      const float vA = __shfl(rA1, k, 64);
      const float vB = __shfl(rB1, k, 64);
      aA0 = fmaf(vA, w0, aA0); aA1 = fmaf(vA, w1, aA1);
      aB0 = fmaf(vB, w0, aB0); aB1 = fmaf(vB, w1, aB1);
    }

    // relu + dropout (scale 2.0)
    aA0 = fmaxf(aA0, 0.0f); aA1 = fmaxf(aA1, 0.0f);
    aB0 = fmaxf(aB0, 0.0f); aB1 = fmaxf(aB1, 0.0f);
    const uint32_t jA = (uint32_t)nA * 128u + (uint32_t)lane;
    const uint32_t jB = (uint32_t)nB * 128u + (uint32_t)lane;
    h[rbA + lane]      = drop_elem(jA)       ? 0.0f : aA0 * 2.0f;
    h[rbA + 64 + lane] = drop_elem(jA + 64u) ? 0.0f : aA1 * 2.0f;
    h[rbB + lane]      = drop_elem(jB)       ? 0.0f : aB0 * 2.0f;
    h[rbB + 64 + lane] = drop_elem(jB + 64u) ? 0.0f : aB1 * 2.0f;
  }
}

// ---------------- fused layer 2 ----------------
// out[n] = (h[n] + sum_{s in adj[n]} h[s]) @ W2 + b2
__global__ __launch_bounds__(512) void gin_fused2(
    const float* __restrict__ h, const int* __restrict__ adj,
    const int* __restrict__ cnt, const float* __restrict__ W2,
    const float* __restrict__ b2, float* __restrict__ out) {
  __shared__ float Wl[128 * 64];  // 32 KB
  for (int i = threadIdx.x; i < 128 * 64 / 4; i += 512)
    reinterpret_cast<float4*>(Wl)[i] = reinterpret_cast<const float4*>(W2)[i];
  __syncthreads();

  const int lane = threadIdx.x & 63;
  const int wid  = threadIdx.x >> 6;
  const float bias = b2[lane];

  for (int p = blockIdx.x * 8 + wid; p < kN / 2; p += gridDim.x * 8) {
    const int nA = p * 2, nB = p * 2 + 1;
    const size_t rbA = (size_t)nA * 128, rbB = (size_t)nB * 128;

    float rA0 = h[rbA + lane], rA1 = h[rbA + 64 + lane];
    float rB0 = h[rbB + lane], rB1 = h[rbB + 64 + lane];
    const int dA = __builtin_amdgcn_readfirstlane(cnt[nA]);
    const int dB = __builtin_amdgcn_readfirstlane(cnt[nB]);
    const int* alA = adj + nA * kCap;
    const int* alB = adj + nB * kCap;
    int e = 0;
    for (; e + 2 <= dA; e += 2) {
      const int s0 = __builtin_amdgcn_readfirstlane(alA[e]);
      const int s1 = __builtin_amdgcn_readfirstlane(alA[e + 1]);
      rA0 += h[(size_t)s0 * 128 + lane] + h[(size_t)s1 * 128 + lane];
      rA1 += h[(size_t)s0 * 128 + 64 + lane] + h[(size_t)s1 * 128 + 64 + lane];
    }
    if (e < dA) {
      const int s = __builtin_amdgcn_readfirstlane(alA[e]);
      rA0 += h[(size_t)s * 128 + lane];
      rA1 += h[(size_t)s * 128 + 64 + lane];
    }
    e = 0;
    for (; e + 2 <= dB; e += 2) {
      const int s0 = __builtin_amdgcn_readfirstlane(alB[e]);
      const int s1 = __builtin_amdgcn_readfirstlane(alB[e + 1]);
      rB0 += h[(size_t)s0 * 128 + lane] + h[(size_t)s1 * 128 + lane];
      rB1 += h[(size_t)s0 * 128 + 64 + lane] + h[(size_t)s1 * 128 + 64 + lane];
    }
    if (e < dB) {
      const int s = __builtin_amdgcn_readfirstlane(alB[e]);
      rB0 += h[(size_t)s * 128 + lane];
      rB1 += h[(size_t)s * 128 + 64 + lane];
    }

    float aA = bias, aB = bias;
#pragma unroll
    for (int k = 0; k < 64; ++k) {
      const float w = Wl[k * 64 + lane];
      aA = fmaf(__shfl(rA0, k, 64), w, aA);
      aB = fmaf(__shfl(rB0, k, 64), w, aB);
    }
#pragma unroll
    for (int k = 0; k < 64; ++k) {
      const float w = Wl[(64 + k) * 64 + lane];
      aA = fmaf(__shfl(rA1, k, 64), w, aA);
      aB = fmaf(__shfl(rB1, k, 64), w, aB);
    }

    out[(size_t)nA * 64 + lane] = aA;
    out[(size_t)nB * 64 + lane] = aB;
  }
}

// ---------------- launch ----------------
extern "C" void kernel_launch(void* const* d_in, const int* in_sizes, int n_in,
                              void* d_out, int out_size, void* d_ws, size_t ws_size,
                              hipStream_t stream) {
  const float* x  = (const float*)d_in[0];
  const int*   ei = (const int*)d_in[1];
  const float* W1 = (const float*)d_in[2];
  const float* b1 = (const float*)d_in[3];
  const float* W2 = (const float*)d_in[4];
  const float* b2 = (const float*)d_in[5];
  float* out = (float*)d_out;

  const int E = in_sizes[1] / 2;  // edge_index is (2, E), int32 on device
  const int* src = ei;
  const int* dst = ei + E;

  int*   cnt = (int*)d_ws;                         // 50000 ints
  int*   adj = cnt + kN;                           // 50000*64 ints = 12.8 MB
  float* h   = (float*)(adj + (size_t)kN * kCap);  // 50000*128 f32 = 25.6 MB

  hipMemsetAsync(cnt, 0, (size_t)kN * sizeof(int), stream);
  build_adj<<<(E + 255) / 256, 256, 0, stream>>>(src, dst, cnt, adj, E);
  gin_fused1<<<512, 512, 0, stream>>>(x, adj, cnt, W1, b1, h);
  gin_fused2<<<1024, 512, 0, stream>>>(h, adj, cnt, W2, b2, out);
}